// Round 1
// baseline (1323.940 us; speedup 1.0000x reference)
//
#include <hip/hip_runtime.h>

#define ALPHA 0.2f

// One node = 16 lanes, each lane owns a float4 segment of F=64.
// 4 metapaths' rows loaded as float4 (wave-coalesced 1 KB per plane),
// dot reduced via 16-lane butterfly shuffle, softmax in registers,
// weighted sum reuses the resident float4s. Input read exactly once.
__global__ __launch_bounds__(256) void metapath_aggr_kernel(
    const float* __restrict__ input,   // [4, N, 64]
    const float* __restrict__ a,       // [64]
    float* __restrict__ out,           // [N, 64]
    int N) {
    const long long tid  = (long long)blockIdx.x * blockDim.x + threadIdx.x;
    const long long node = tid >> 4;         // 16 lanes per node
    const int       seg  = (int)(tid & 15);  // float4 segment index within F=64
    if (node >= N) return;

    const float4 av = ((const float4*)a)[seg];

    const long long base    = node * 64 + (long long)seg * 4;
    const long long mstride = (long long)N * 64;

    const float4 x0 = *(const float4*)(input + base);
    const float4 x1 = *(const float4*)(input + base + mstride);
    const float4 x2 = *(const float4*)(input + base + 2 * mstride);
    const float4 x3 = *(const float4*)(input + base + 3 * mstride);

    float e0 = x0.x * av.x + x0.y * av.y + x0.z * av.z + x0.w * av.w;
    float e1 = x1.x * av.x + x1.y * av.y + x1.z * av.z + x1.w * av.w;
    float e2 = x2.x * av.x + x2.y * av.y + x2.z * av.z + x2.w * av.w;
    float e3 = x3.x * av.x + x3.y * av.y + x3.z * av.z + x3.w * av.w;

    // Reduce partial dots across the 16 lanes of this node (xor stays in-group).
    #pragma unroll
    for (int m = 8; m >= 1; m >>= 1) {
        e0 += __shfl_xor(e0, m, 64);
        e1 += __shfl_xor(e1, m, 64);
        e2 += __shfl_xor(e2, m, 64);
        e3 += __shfl_xor(e3, m, 64);
    }

    // LeakyReLU
    e0 = (e0 >= 0.f) ? e0 : ALPHA * e0;
    e1 = (e1 >= 0.f) ? e1 : ALPHA * e1;
    e2 = (e2 >= 0.f) ? e2 : ALPHA * e2;
    e3 = (e3 >= 0.f) ? e3 : ALPHA * e3;

    // Softmax over the 4 metapaths (registers only).
    const float mx = fmaxf(fmaxf(e0, e1), fmaxf(e2, e3));
    float w0 = __expf(e0 - mx);
    float w1 = __expf(e1 - mx);
    float w2 = __expf(e2 - mx);
    float w3 = __expf(e3 - mx);
    const float inv = 1.0f / (w0 + w1 + w2 + w3);
    w0 *= inv; w1 *= inv; w2 *= inv; w3 *= inv;

    float4 o;
    o.x = w0 * x0.x + w1 * x1.x + w2 * x2.x + w3 * x3.x;
    o.y = w0 * x0.y + w1 * x1.y + w2 * x2.y + w3 * x3.y;
    o.z = w0 * x0.z + w1 * x1.z + w2 * x2.z + w3 * x3.z;
    o.w = w0 * x0.w + w1 * x1.w + w2 * x2.w + w3 * x3.w;

    *(float4*)(out + base) = o;
}

extern "C" void kernel_launch(void* const* d_in, const int* in_sizes, int n_in,
                              void* d_out, int out_size, void* d_ws, size_t ws_size,
                              hipStream_t stream) {
    const float* input = (const float*)d_in[0];   // [4, N, 64] fp32
    const float* a     = (const float*)d_in[1];   // [64, 1] fp32
    float* out         = (float*)d_out;           // [N, 64] fp32

    const int N = in_sizes[0] / (4 * 64);

    const long long total_threads = (long long)N * 16;
    const int block = 256;
    const int grid  = (int)((total_threads + block - 1) / block);

    metapath_aggr_kernel<<<grid, block, 0, stream>>>(input, a, out, N);
}